// Round 6
// baseline (207.292 us; speedup 1.0000x reference)
//
#include <hip/hip_runtime.h>
#include <math.h>

// Problem constants
#define BATCH 2
#define SEQ   2048
#define NH    16
#define HD    64
#define DM    1024
#define MROWS (BATCH * SEQ)                  // 4096
#define NEL   ((size_t)MROWS * DM)           // 4 M elements (activation buffer)
#define WEL   ((size_t)DM * DM)              // 1 M elements (weight buffer)
// softmax scale folded into Q at projection: 1/sqrt(64) * log2(e)
#define SM_SCALE_LOG2E 0.18033688011112042f

typedef __bf16 bf16x8 __attribute__((ext_vector_type(8)));
typedef float  f32x4  __attribute__((ext_vector_type(4)));

#define MFMA16(a, b, c) __builtin_amdgcn_mfma_f32_16x16x32_bf16((a), (b), (c), 0, 0, 0)
#define EXP2(x) __builtin_amdgcn_exp2f(x)

// async global->LDS, 16B per lane; LDS dest = wave-uniform base + lane*16
#define GLDS16(g, s) __builtin_amdgcn_global_load_lds( \
    (const __attribute__((address_space(1))) void*)(g), \
    (__attribute__((address_space(3))) void*)(s), 16, 0, 0)

// ======================================================================
// fp32 -> bf16 converts
// ======================================================================
__global__ __launch_bounds__(256) void cvt_x(const float* __restrict__ src,
                                             __bf16* __restrict__ dst) {
    const size_t i = ((size_t)blockIdx.x * 256 + threadIdx.x) * 4;
    const float4 f = *(const float4*)&src[i];
    __bf16 b[4] = {(__bf16)f.x, (__bf16)f.y, (__bf16)f.z, (__bf16)f.w};
    *(ushort4*)&dst[i] = *(ushort4*)b;
}

__global__ __launch_bounds__(256) void cvt_w(const float* __restrict__ w0,
                                             const float* __restrict__ w1,
                                             const float* __restrict__ w2,
                                             const float* __restrict__ w3,
                                             __bf16* __restrict__ dst) {
    const int z = blockIdx.z;
    const float* src = (z == 0) ? w0 : (z == 1) ? w1 : (z == 2) ? w2 : w3;
    __bf16* d = dst + (size_t)z * WEL;
    const size_t i = ((size_t)blockIdx.x * 256 + threadIdx.x) * 4;
    const float4 f = *(const float4*)&src[i];
    __bf16 b[4] = {(__bf16)f.x, (__bf16)f.y, (__bf16)f.z, (__bf16)f.w};
    *(ushort4*)&d[i] = *(ushort4*)b;
}

// ======================================================================
// NT bf16 MFMA GEMM, single-barrier double-buffered K-loop,
// parameterized on block tile and wave count for occupancy tuning.
//   BM x BN tile, TB threads (TB/64 waves), wave tile (MT*16) x (NT*16).
//   Requires BM/16 == BN/16 == TB/64 (one A + one B staging instr/wave).
// mode 1: z selects weight+output slab; bf16 store permuted to
//   (B,H,S,HD); z==0 (Q) pre-scaled; z==2 (V) dual-stored to Vt.
// mode 0: fp32 row-major M x DM store.
// ======================================================================
template<int BM, int BN, int TB, int MT, int NT>
__global__ __launch_bounds__(TB, 4) void gemm_nt_mfma(
    const __bf16* __restrict__ A, const __bf16* __restrict__ W0,
    void* __restrict__ C0, __bf16* __restrict__ Vt, int mode)
{
    constexpr int NIT   = DM / 32;          // 32 K-iterations
    constexpr int WCOLS = BN / (NT * 16);   // waves per column band
    __shared__ __bf16 Ast[2][BM * 32];
    __shared__ __bf16 Bst[2][BN * 32];

    const int t = threadIdx.x;
    const int w = t >> 6, l = t & 63;
    const int quad = l >> 4, l15 = l & 15;
    const int z = blockIdx.z;
    const int m0 = blockIdx.y * BM, n0 = blockIdx.x * BN;
    const int wm = (w / WCOLS) * (MT * 16);
    const int wn = (w % WCOLS) * (NT * 16);

    const __bf16* Wp = W0 + (size_t)z * WEL;

    const int lrow = l >> 2;           // staging: lane row within 16-row instr
    const int lkof = (l & 3) * 8;      // staging: lane k-offset
    const __bf16* Ag = A  + (size_t)(m0 + w * 16 + lrow) * DM + lkof;
    const __bf16* Bg = Wp + (size_t)(n0 + w * 16 + lrow) * DM + lkof;
    const int soff = (w * 16) * 32;    // wave-uniform LDS offset

    f32x4 acc[MT][NT];
    #pragma unroll
    for (int i = 0; i < MT; i++)
        #pragma unroll
        for (int j = 0; j < NT; j++) acc[i][j] = (f32x4)0.0f;

    // prologue: tile 0 -> buf 0
    GLDS16(Ag, &Ast[0][soff]);
    GLDS16(Bg, &Bst[0][soff]);
    __syncthreads();

    for (int i = 0; i < NIT; i++) {
        const int cur = i & 1, nxt = cur ^ 1;
        if (i + 1 < NIT) {
            const int k0 = (i + 1) * 32;
            GLDS16(Ag + k0, &Ast[nxt][soff]);
            GLDS16(Bg + k0, &Bst[nxt][soff]);
        }

        bf16x8 af[MT], bfr[NT];
        #pragma unroll
        for (int mi = 0; mi < MT; mi++)
            af[mi] = *(const bf16x8*)&Ast[cur][(wm + mi * 16 + l15) * 32 + quad * 8];
        #pragma unroll
        for (int ni = 0; ni < NT; ni++)
            bfr[ni] = *(const bf16x8*)&Bst[cur][(wn + ni * 16 + l15) * 32 + quad * 8];
        #pragma unroll
        for (int mi = 0; mi < MT; mi++)
            #pragma unroll
            for (int ni = 0; ni < NT; ni++)
                acc[mi][ni] = MFMA16(af[mi], bfr[ni], acc[mi][ni]);

        __syncthreads();   // single barrier: drains prefetch, fences buffers
    }

    if (mode) {
        const float sc = (z == 0) ? SM_SCALE_LOG2E : 1.0f;
        __bf16* C = (__bf16*)C0 + (size_t)z * NEL;
        #pragma unroll
        for (int mi = 0; mi < MT; mi++)
            #pragma unroll
            for (int ni = 0; ni < NT; ni++)
                #pragma unroll
                for (int r = 0; r < 4; r++) {
                    const int row = m0 + wm + mi * 16 + quad * 4 + r;
                    const int col = n0 + wn + ni * 16 + l15;
                    const int b = row >> 11, s = row & (SEQ - 1);
                    const int h = col >> 6,  d = col & (HD - 1);
                    const __bf16 val = (__bf16)(acc[mi][ni][r] * sc);
                    C[((size_t)(b * NH + h) * SEQ + s) * HD + d] = val;
                    if (z == 2)   // V: also store transposed (B,H,HD,S)
                        Vt[((size_t)(b * NH + h) * HD + d) * SEQ + s] = val;
                }
    } else {
        float* C = (float*)C0;
        #pragma unroll
        for (int mi = 0; mi < MT; mi++)
            #pragma unroll
            for (int ni = 0; ni < NT; ni++)
                #pragma unroll
                for (int r = 0; r < 4; r++) {
                    const int row = m0 + wm + mi * 16 + quad * 4 + r;
                    const int col = n0 + wn + ni * 16 + l15;
                    C[(size_t)row * DM + col] = acc[mi][ni][r];
                }
    }
}

// ======================================================================
// Flash attention v5: transposed-score MFMA, fixed-shift softmax, fused
// subtract-projection, Q-in-registers, single-barrier dbuf K/V staging.
// NOW 512-thread blocks: 8 waves x 16 queries (same 128-q block, same
// LDS) -> 2 blocks/CU = 16 waves/CU (was 8) for latency hiding.
// ======================================================================
__global__ __launch_bounds__(512, 4) void attn_mfma(
    const __bf16* __restrict__ Q, const __bf16* __restrict__ K,
    const __bf16* __restrict__ Vt, const __bf16* __restrict__ V,
    const float* __restrict__ xsa, __bf16* __restrict__ X2)
{
    // KV[buf][0] = K region [half][key][32]; KV[buf][1] = V region
    // [keyhalf][dim][32]. Each region 4096 elems (8 KB).
    __shared__ __bf16 KV[2][2][2 * 64 * 32];
    __shared__ __bf16 Pt[8][16][72];   // per-wave P [q][key+pad]  18 KB

    const int t = threadIdx.x;
    const int w = t >> 6, l = t & 63;
    const int quad = l >> 4, l15 = l & 15;
    const int bh = blockIdx.y;
    const int q0 = blockIdx.x * 128;

    const __bf16* Qb  = Q  + (size_t)bh * SEQ * HD;
    const __bf16* Kb  = K  + (size_t)bh * SEQ * HD;
    const __bf16* Vtb = Vt + (size_t)bh * HD * SEQ;

    const int lrow = l >> 2;
    const int lkof = (l & 3) * 8;

    // staging assignment (per tile): wave w stages one 16-row K instr and
    // one 16-row V instr:  half = w&1, row band = (w>>1)*16.
    const int sh  = w & 1;           // which 32-dim (K) / 32-key (V) half
    const int sr  = (w >> 1) * 16;   // row band

    // ---- prologue: stage Q into KV[1] (16 KB overlay) + K0/V0 into KV[0]
    __bf16* Qst = &KV[1][0][0];   // flat [h][q][32]: h*4096 + q*32
    #pragma unroll
    for (int h = 0; h < 2; h++)
        GLDS16(Qb + (size_t)(q0 + w * 16 + lrow) * HD + h * 32 + lkof,
               Qst + h * 4096 + (w * 16) * 32);
    GLDS16(Kb + (size_t)(sr + lrow) * HD + sh * 32 + lkof,
           &KV[0][0][sh * 2048 + sr * 32]);
    GLDS16(Vtb + (size_t)(sr + lrow) * SEQ + sh * 32 + lkof,
           &KV[0][1][sh * 2048 + sr * 32]);
    __syncthreads();   // all prologue staging visible

    // ---- hoist Q fragments to registers (loop-invariant) ----
    bf16x8 qf[2];   // [half]
    #pragma unroll
    for (int h = 0; h < 2; h++)
        qf[h] = *(const bf16x8*)&Qst[h * 4096 + (w * 16 + l15) * 32 + quad * 8];
    __syncthreads();   // Q reads done before kt=0 prefetch overwrites KV[1]

    float l_i = 0.0f;
    f32x4 o[4];
    #pragma unroll
    for (int db = 0; db < 4; db++) o[db] = (f32x4)0.0f;

    constexpr int NTILES = SEQ / 64;   // 32 key tiles
    for (int kt = 0; kt < NTILES; kt++) {
        const int cur = kt & 1, nxt = cur ^ 1;
        if (kt + 1 < NTILES) {
            const int k0n = (kt + 1) * 64;
            GLDS16(Kb + (size_t)(k0n + sr + lrow) * HD + sh * 32 + lkof,
                   &KV[nxt][0][sh * 2048 + sr * 32]);
            GLDS16(Vtb + (size_t)(sr + lrow) * SEQ + k0n + sh * 32 + lkof,
                   &KV[nxt][1][sh * 2048 + sr * 32]);
        }
        const __bf16* Ks = &KV[cur][0][0];
        const __bf16* Vs = &KV[cur][1][0];

        // ---- S^T = K Q^T : 64k x 16q x 64d per wave (8 MFMAs) ----
        f32x4 st[4];
        #pragma unroll
        for (int kb = 0; kb < 4; kb++) st[kb] = (f32x4)0.0f;
        #pragma unroll
        for (int h = 0; h < 2; h++)
            #pragma unroll
            for (int kb = 0; kb < 4; kb++) {
                const bf16x8 kf = *(const bf16x8*)&Ks[h * 2048 +
                                      (kb * 16 + l15) * 32 + quad * 8];
                st[kb] = MFMA16(kf, qf[h], st[kb]);
            }

        // ---- fixed-shift softmax: p = exp2(s), accumulate l ----
        float rs = 0.0f;
        #pragma unroll
        for (int kb = 0; kb < 4; kb++)
            #pragma unroll
            for (int r = 0; r < 4; r++) {
                const float p = EXP2(st[kb][r]);
                st[kb][r] = p;
                rs += p;
            }
        rs += __shfl_xor(rs, 16);
        rs += __shfl_xor(rs, 32);
        l_i += rs;
        #pragma unroll
        for (int kb = 0; kb < 4; kb++) {
            __bf16 pb[4] = {(__bf16)st[kb][0], (__bf16)st[kb][1],
                            (__bf16)st[kb][2], (__bf16)st[kb][3]};
            *(uint2*)&Pt[w][l15][kb * 16 + quad * 4] = *(uint2*)pb;
        }

        // ---- O^T += V^T P^T : 64d x 16q x 64k per wave (8 MFMAs) ----
        #pragma unroll
        for (int kh = 0; kh < 2; kh++) {
            const bf16x8 pf = *(const bf16x8*)&Pt[w][l15][kh * 32 + quad * 8];
            #pragma unroll
            for (int db = 0; db < 4; db++) {
                const bf16x8 vf = *(const bf16x8*)&Vs[kh * 2048 +
                                      (db * 16 + l15) * 32 + quad * 8];
                o[db] = MFMA16(vf, pf, o[db]);
            }
        }

        __syncthreads();   // single barrier: drains prefetch, fences buffers
    }

    // ---- epilogue: normalize, fused subtract-projection, store X2 ----
    const float xs = xsa[0];
    const int b = bh >> 4, h = bh & (NH - 1);
    const __bf16* Vb = V + (size_t)bh * SEQ * HD;
    {
        const int q = q0 + w * 16 + l15;   // sequence position
        const float inv = 1.0f / l_i;
        float vv[4][4], on[4][4];
        float dp = 0.0f, nn = 0.0f;
        #pragma unroll
        for (int db = 0; db < 4; db++) {
            __bf16 vb4[4];
            *(uint2*)vb4 = *(const uint2*)&Vb[(size_t)q * HD + db * 16 + quad * 4];
            #pragma unroll
            for (int r = 0; r < 4; r++) {
                const float vf = (float)vb4[r];
                const float of = o[db][r] * inv;
                vv[db][r] = vf;
                on[db][r] = of;
                dp += of * vf;
                nn += vf * vf;
            }
        }
        dp += __shfl_xor(dp, 16); dp += __shfl_xor(dp, 32);
        nn += __shfl_xor(nn, 16); nn += __shfl_xor(nn, 32);
        const float coef = xs * dp / (nn + 1e-8f);
        #pragma unroll
        for (int db = 0; db < 4; db++) {
            __bf16 ob[4];
            #pragma unroll
            for (int r = 0; r < 4; r++)
                ob[r] = (__bf16)(on[db][r] - coef * vv[db][r]);
            *(uint2*)&X2[((size_t)b * SEQ + q) * DM + h * HD + db * 16 + quad * 4] =
                *(uint2*)ob;
        }
    }
}

// ======================================================================
extern "C" void kernel_launch(void* const* d_in, const int* in_sizes, int n_in,
                              void* d_out, int out_size, void* d_ws, size_t ws_size,
                              hipStream_t stream)
{
    (void)in_sizes; (void)n_in; (void)out_size; (void)ws_size;
    const float* x   = (const float*)d_in[0];
    const float* Wq  = (const float*)d_in[1];
    const float* Wk  = (const float*)d_in[2];
    const float* Wv  = (const float*)d_in[3];
    const float* Wo  = (const float*)d_in[4];
    const float* xsa = (const float*)d_in[5];
    float* out = (float*)d_out;

    // workspace layout (bf16 elements): 56 MB total
    __bf16* xb  = (__bf16*)d_ws;        // 4 M
    __bf16* Wb  = xb  + NEL;            // 4 x 1 M (Wq,Wk,Wv,Wo)
    __bf16* Qb  = Wb  + 4 * WEL;        // 4 M  (B,H,S,HD), pre-scaled
    __bf16* Kb  = Qb  + NEL;            // 4 M
    __bf16* Vb  = Kb  + NEL;            // 4 M
    __bf16* Vtb = Vb  + NEL;            // 4 M  (B,H,HD,S)
    __bf16* X2  = Vtb + NEL;            // 4 M  (B,S,DM)

    cvt_x<<<dim3(NEL / 1024), 256, 0, stream>>>(x, xb);
    cvt_w<<<dim3(WEL / 1024, 1, 4), 256, 0, stream>>>(Wq, Wk, Wv, Wo, Wb);

    // Q/K/V projections: 512-thread blocks, 128x128 tile, 24 waves/CU
    gemm_nt_mfma<128, 128, 512, 4, 2>
        <<<dim3(DM / 128, MROWS / 128, 3), 512, 0, stream>>>(xb, Wb, Qb, Vtb, 1);

    // attention + fused subtract-projection -> X2 (512-thread blocks)
    attn_mfma<<<dim3(SEQ / 128, BATCH * NH), 512, 0, stream>>>(
        Qb, Kb, Vtb, Vb, xsa, X2);

    // output projection: 64x64 tile -> 1024 blocks = 4/CU, fp32 out
    gemm_nt_mfma<64, 64, 256, 2, 2>
        <<<dim3(DM / 64, MROWS / 64, 1), 256, 0, stream>>>(
        X2, Wb + 3 * WEL, out, nullptr, 0);
}